// Round 1
// baseline (2007.519 us; speedup 1.0000x reference)
//
#include <hip/hip_runtime.h>
#include <math.h>

// ---- problem constants ----
#define NN     50000
#define NE     400000
#define INDIM  256
#define NH     128
#define NTYPE  4
#define NREL   5
#define NHEAD  4
#define DK     32
#define RSQRT_DK 0.17677669529663687f
#define BN     64
#define EPB    8

__device__ __forceinline__ float gelu_f(float x){
    return 0.5f * x * (1.0f + erff(x * 0.70710678118654752f));
}
// monotone float<->uint key for atomicMax on signed floats
__device__ __forceinline__ unsigned fkey(float f){
    unsigned u = __float_as_uint(f);
    return (u & 0x80000000u) ? ~u : (u | 0x80000000u);
}
__device__ __forceinline__ float funkey(unsigned u){
    return (u & 0x80000000u) ? __uint_as_float(u & 0x7fffffffu) : __uint_as_float(~u);
}

// ---------------- bucketing (recomputed every call; order within bucket arbitrary) ---------
__global__ void GNN_ehist(const int* __restrict__ etype, int* __restrict__ ecnt){
    __shared__ int l[8];
    if (threadIdx.x < 8) l[threadIdx.x] = 0;
    __syncthreads();
    int e = blockIdx.x * 256 + threadIdx.x;
    if (e < NE) atomicAdd(&l[etype[e]], 1);
    __syncthreads();
    if (threadIdx.x < NREL && l[threadIdx.x]) atomicAdd(&ecnt[threadIdx.x], l[threadIdx.x]);
}

__global__ void GNN_eprefix(const int* __restrict__ ecnt, int* __restrict__ ecur){
    if (threadIdx.x == 0){
        int s = 0;
        for (int r = 0; r < NREL; r++){ ecur[r] = s; s += ecnt[r]; }
    }
}

__global__ void GNN_nscatter(const int* __restrict__ ntype, int* __restrict__ ncur,
                             int* __restrict__ nperm){
    __shared__ int lcnt[4], lbase[4];
    int tid = threadIdx.x;
    if (tid < 4) lcnt[tid] = 0;
    __syncthreads();
    int n = blockIdx.x * 256 + tid;
    int t = 0, lpos = 0;
    bool ok = (n < NN);
    if (ok){ t = ntype[n]; lpos = atomicAdd(&lcnt[t], 1); }
    __syncthreads();
    if (tid < 4 && lcnt[tid] > 0) lbase[tid] = atomicAdd(&ncur[tid], lcnt[tid]);
    __syncthreads();
    if (ok) nperm[t * NN + lbase[t] + lpos] = n;
}

__global__ void GNN_escatter(const int* __restrict__ etype, int* __restrict__ ecur,
                             int* __restrict__ eperm){
    __shared__ int lcnt[8], lbase[8];
    int tid = threadIdx.x;
    if (tid < 8) lcnt[tid] = 0;
    __syncthreads();
    int e = blockIdx.x * 256 + tid;
    int r = 0, lpos = 0;
    bool ok = (e < NE);
    if (ok){ r = etype[e]; lpos = atomicAdd(&lcnt[r], 1); }
    __syncthreads();
    if (tid < NREL && lcnt[tid] > 0) lbase[tid] = atomicAdd(&ecur[tid], lcnt[tid]);
    __syncthreads();
    if (ok) eperm[lbase[r] + lpos] = e;
}

// ------------- per-type tiled GEMM: OUT[n,:] = epilogue( X[n,:] @ W[type(n)] + b[type(n)] )
// MODE 0: gelu(.)   MODE 1: identity   MODE 2: (.)*sig(skip[t]) + Hprev*(1-sig(skip[t]))
template<int MODE>
__global__ __launch_bounds__(256) void GNN_ptype_gemm(
    const float* __restrict__ X, int K,
    const float* __restrict__ Wall, const float* __restrict__ ball,
    const float* __restrict__ skiprow, const float* __restrict__ Hprev,
    const int* __restrict__ nperm, const int* __restrict__ counts,
    float* __restrict__ OUT)
{
    int t = blockIdx.y;
    int cnt = counts[t];
    int rbase = blockIdx.x * BN;
    if (rbase >= cnt) return;
    const float* W = Wall + (size_t)t * K * NH;
    __shared__ float Xs[BN][33];          // +1 pad breaks bank aliasing
    __shared__ float Ws[32][NH];
    __shared__ int nids[BN];
    int tid = threadIdx.x;
    if (tid < BN){
        int idx = rbase + tid;
        nids[tid] = (idx < cnt) ? nperm[t * NN + idx] : -1;
    }
    int cq = tid & 31;    // cols cq*4 .. cq*4+3
    int rq = tid >> 5;    // rows rq + 8*i
    float acc[8][4];
    #pragma unroll
    for (int i = 0; i < 8; i++){ acc[i][0]=0.f; acc[i][1]=0.f; acc[i][2]=0.f; acc[i][3]=0.f; }
    __syncthreads();
    for (int k0 = 0; k0 < K; k0 += 32){
        {   // X tile: 64 rows x 32 k (gathered rows)
            int lr = tid >> 3;
            int lc = (tid & 7) * 4;
            #pragma unroll
            for (int h2 = 0; h2 < 2; h2++){
                int r = lr + 32 * h2;
                int nid = nids[r];
                float4 xv = make_float4(0.f, 0.f, 0.f, 0.f);
                if (nid >= 0) xv = *(const float4*)(X + (size_t)nid * K + k0 + lc);
                Xs[r][lc+0]=xv.x; Xs[r][lc+1]=xv.y; Xs[r][lc+2]=xv.z; Xs[r][lc+3]=xv.w;
            }
        }
        {   // W tile: 32 k x 128 cols
            int wr = tid >> 5;
            int wc = (tid & 31) * 4;
            #pragma unroll
            for (int h2 = 0; h2 < 4; h2++){
                int r = wr + 8 * h2;
                *(float4*)&Ws[r][wc] = *(const float4*)(W + (size_t)(k0 + r) * NH + wc);
            }
        }
        __syncthreads();
        #pragma unroll
        for (int kk = 0; kk < 32; kk++){
            float4 wv = *(const float4*)&Ws[kk][cq * 4];
            #pragma unroll
            for (int i = 0; i < 8; i++){
                float xv = Xs[rq + 8*i][kk];
                acc[i][0] += xv * wv.x; acc[i][1] += xv * wv.y;
                acc[i][2] += xv * wv.z; acc[i][3] += xv * wv.w;
            }
        }
        __syncthreads();
    }
    float b0 = ball[t*NH + cq*4 + 0];
    float b1 = ball[t*NH + cq*4 + 1];
    float b2 = ball[t*NH + cq*4 + 2];
    float b3 = ball[t*NH + cq*4 + 3];
    float a_t = 0.f, one_m = 0.f;
    if (MODE == 2){ a_t = 1.f / (1.f + expf(-skiprow[t])); one_m = 1.f - a_t; }
    #pragma unroll
    for (int i = 0; i < 8; i++){
        int r = rq + 8*i;
        int nid = nids[r];
        if (nid < 0) continue;
        float v0 = acc[i][0] + b0, v1 = acc[i][1] + b1;
        float v2 = acc[i][2] + b2, v3 = acc[i][3] + b3;
        if (MODE == 0){ v0 = gelu_f(v0); v1 = gelu_f(v1); v2 = gelu_f(v2); v3 = gelu_f(v3); }
        if (MODE == 2){
            float4 hp = *(const float4*)(Hprev + (size_t)nid * NH + cq * 4);
            v0 = v0 * a_t + hp.x * one_m; v1 = v1 * a_t + hp.y * one_m;
            v2 = v2 * a_t + hp.z * one_m; v3 = v3 * a_t + hp.w * one_m;
        }
        *(float4*)(OUT + (size_t)nid * NH + cq * 4) = make_float4(v0, v1, v2, v3);
    }
}

// ------------- RTE tables: rtab[m] = rte_emb[m]@rte_W[l] + rte_b[l];  RK/RV[t][m] = rtab[m]@W{k,v}[l][t]
__global__ void GNN_rte_tab(const float* __restrict__ rte_emb, const float* __restrict__ rW,
                            const float* __restrict__ rb, float* __restrict__ tab){
    int m = blockIdx.x, j = threadIdx.x;
    __shared__ float e[NH];
    e[j] = rte_emb[m * NH + j];
    __syncthreads();
    float a = rb[j];
    #pragma unroll 8
    for (int d = 0; d < NH; d++) a += e[d] * rW[d * NH + j];
    tab[m * NH + j] = a;
}

__global__ void GNN_rte_proj(const float* __restrict__ tab, const float* __restrict__ WkL,
                             const float* __restrict__ WvL, float* __restrict__ RK,
                             float* __restrict__ RV){
    int m = blockIdx.x, j = threadIdx.x;
    int sel = blockIdx.y; int t = sel >> 1; int which = sel & 1;
    const float* W = (which ? WvL : WkL) + (size_t)t * NH * NH;
    float* O = which ? RV : RK;
    __shared__ float e[NH];
    e[j] = tab[m * NH + j];
    __syncthreads();
    float a = 0.f;
    #pragma unroll 8
    for (int d = 0; d < NH; d++) a += e[d] * W[d * NH + j];
    O[(size_t)(t * 240 + m) * NH + j] = a;
}

// ------------- E1: attention scores + segment max (atomic on monotone key)
__global__ __launch_bounds__(128) void GNN_edge_att(
    const float* __restrict__ Kn, const float* __restrict__ Qn, const float* __restrict__ RK,
    const int* __restrict__ eperm, const int* __restrict__ esrc, const int* __restrict__ edst,
    const int* __restrict__ etype, const int* __restrict__ etime, const int* __restrict__ ntype,
    const float* __restrict__ relA, const float* __restrict__ relP,
    float* __restrict__ att, unsigned int* __restrict__ amax)
{
    __shared__ float ra[NHEAD * DK * DK];   // 16 KB: rel_att[r] staged per block
    __shared__ float kb[NH];
    int tid = threadIdx.x;
    int head = tid >> 5, c = tid & 31;
    int cur_r = -1;
    int base = blockIdx.x * EPB;
    for (int ei = 0; ei < EPB; ei++){
        int idx = base + ei;
        if (idx >= NE) break;
        int e = eperm[idx];
        int r = etype[e];
        if (r != cur_r){   // uniform branch; prev-iter barrier protects ra reuse
            const float4* srcp = (const float4*)(relA + (size_t)r * NHEAD * DK * DK);
            #pragma unroll
            for (int i = 0; i < 8; i++) ((float4*)ra)[tid + i * 128] = srcp[tid + i * 128];
            cur_r = r;
        }
        int s = esrc[e], d = edst[e], tm = etime[e];
        int st = ntype[s];
        kb[tid] = Kn[(size_t)s * NH + tid] + RK[(size_t)(st * 240 + tm) * NH + tid];
        __syncthreads();
        const float* rah = ra + head * DK * DK;
        float kr = 0.f;
        #pragma unroll
        for (int dd = 0; dd < DK; dd++) kr += kb[head * DK + dd] * rah[dd * DK + c];
        float pv = Qn[(size_t)d * NH + tid] * kr;
        #pragma unroll
        for (int off = 16; off > 0; off >>= 1) pv += __shfl_xor(pv, off, 32);
        if (c == 0){
            float a = pv * relP[r * NHEAD + head] * RSQRT_DK;
            att[(size_t)e * NHEAD + head] = a;
            atomicMax(&amax[(size_t)d * NHEAD + head], fkey(a));
        }
        __syncthreads();
    }
}

// ------------- E2: ex = exp(att - amax); denom += ex; aggr += msg*ex (normalize later)
__global__ __launch_bounds__(128) void GNN_edge_msg(
    const float* __restrict__ Vn, const float* __restrict__ RV,
    const int* __restrict__ eperm, const int* __restrict__ esrc, const int* __restrict__ edst,
    const int* __restrict__ etype, const int* __restrict__ etime, const int* __restrict__ ntype,
    const float* __restrict__ relM, const float* __restrict__ att,
    const unsigned int* __restrict__ amax,
    float* __restrict__ denom, float* __restrict__ aggr)
{
    __shared__ float rm[NHEAD * DK * DK];
    __shared__ float vb[NH];
    int tid = threadIdx.x;
    int head = tid >> 5, c = tid & 31;
    int cur_r = -1;
    int base = blockIdx.x * EPB;
    for (int ei = 0; ei < EPB; ei++){
        int idx = base + ei;
        if (idx >= NE) break;
        int e = eperm[idx];
        int r = etype[e];
        if (r != cur_r){
            const float4* srcp = (const float4*)(relM + (size_t)r * NHEAD * DK * DK);
            #pragma unroll
            for (int i = 0; i < 8; i++) ((float4*)rm)[tid + i * 128] = srcp[tid + i * 128];
            cur_r = r;
        }
        int s = esrc[e], d = edst[e], tm = etime[e];
        int st = ntype[s];
        vb[tid] = Vn[(size_t)s * NH + tid] + RV[(size_t)(st * 240 + tm) * NH + tid];
        __syncthreads();
        const float* rmh = rm + head * DK * DK;
        float mr = 0.f;
        #pragma unroll
        for (int dd = 0; dd < DK; dd++) mr += vb[head * DK + dd] * rmh[dd * DK + c];
        float amx = funkey(amax[(size_t)d * NHEAD + head]);
        float ex = expf(att[(size_t)e * NHEAD + head] - amx);
        atomicAdd(&aggr[(size_t)d * NH + tid], mr * ex);
        if (c == 0) atomicAdd(&denom[(size_t)d * NHEAD + head], ex);
        __syncthreads();
    }
}

// ------------- normalize + gelu (in place on aggr)
__global__ void GNN_norm_gelu(const float* __restrict__ denom, float* __restrict__ aggr){
    int idx = blockIdx.x * 256 + threadIdx.x;
    if (idx >= NN * NH) return;
    int n = idx >> 7, j = idx & 127;
    float v = aggr[idx] / (denom[n * NHEAD + (j >> 5)] + 1e-16f);
    aggr[idx] = gelu_f(v);
}

extern "C" void kernel_launch(void* const* d_in, const int* in_sizes, int n_in,
                              void* d_out, int out_size, void* d_ws, size_t ws_size,
                              hipStream_t stream)
{
    const float* node_feature = (const float*)d_in[0];
    const float* adapt_W = (const float*)d_in[1];
    const float* adapt_b = (const float*)d_in[2];
    const float* Wk = (const float*)d_in[3];
    const float* bk = (const float*)d_in[4];
    const float* Wq = (const float*)d_in[5];
    const float* bq = (const float*)d_in[6];
    const float* Wv = (const float*)d_in[7];
    const float* bv = (const float*)d_in[8];
    const float* Wa = (const float*)d_in[9];
    const float* ba = (const float*)d_in[10];
    const float* rel_pri = (const float*)d_in[11];
    const float* rel_att = (const float*)d_in[12];
    const float* rel_msg = (const float*)d_in[13];
    const float* skip = (const float*)d_in[14];
    const float* rte_emb = (const float*)d_in[15];
    const float* rte_W = (const float*)d_in[16];
    const float* rte_b = (const float*)d_in[17];
    const int* node_type = (const int*)d_in[18];
    const int* edge_index = (const int*)d_in[19];
    const int* edge_type = (const int*)d_in[20];
    const int* edge_time = (const int*)d_in[21];
    const int* esrc = edge_index;          // row 0 = source j
    const int* edst = edge_index + NE;     // row 1 = target i

    char* p = (char*)d_ws;
    auto alloc = [&](size_t bytes) -> char* {
        char* r = p; p += (bytes + 255) & ~(size_t)255; return r;
    };
    float* hA    = (float*)alloc((size_t)NN * NH * 4);
    float* hB    = (float*)alloc((size_t)NN * NH * 4);
    float* Qn    = (float*)alloc((size_t)NN * NH * 4);
    float* Kn    = (float*)alloc((size_t)NN * NH * 4);
    float* Vn    = (float*)alloc((size_t)NN * NH * 4);
    unsigned* amax = (unsigned*)alloc((size_t)NN * NHEAD * 4);  // contiguous with denom+aggr
    float* denom = (float*)alloc((size_t)NN * NHEAD * 4);       // (one memset covers all 3)
    float* aggr  = (float*)alloc((size_t)NN * NH * 4);
    float* att   = (float*)alloc((size_t)NE * NHEAD * 4);
    float* rtab  = (float*)alloc((size_t)240 * NH * 4);
    float* RK    = (float*)alloc((size_t)NTYPE * 240 * NH * 4);
    float* RV    = (float*)alloc((size_t)NTYPE * 240 * NH * 4);
    int* nperm   = (int*)alloc((size_t)NTYPE * NN * 4);
    int* eperm   = (int*)alloc((size_t)NE * 4);
    int* cnts    = (int*)alloc(64);
    int* ncur = cnts;        // [4]  node cursors -> final per-type counts
    int* ecnt = cnts + 4;    // [5]
    int* ecur = cnts + 9;    // [5]

    hipMemsetAsync(cnts, 0, 64, stream);
    GNN_ehist<<<(NE + 255) / 256, 256, 0, stream>>>(edge_type, ecnt);
    GNN_eprefix<<<1, 64, 0, stream>>>(ecnt, ecur);
    GNN_nscatter<<<(NN + 255) / 256, 256, 0, stream>>>(node_type, ncur, nperm);
    GNN_escatter<<<(NE + 255) / 256, 256, 0, stream>>>(edge_type, ecur, eperm);

    dim3 ggrid((NN + BN - 1) / BN, NTYPE);
    // h = gelu(per_type_linear(x, adapt))
    GNN_ptype_gemm<0><<<ggrid, 256, 0, stream>>>(node_feature, INDIM, adapt_W, adapt_b,
                                                 nullptr, nullptr, nperm, ncur, hA);
    const float* hin = hA;
    for (int l = 0; l < 2; l++){
        const float* WkL = Wk + (size_t)l * NTYPE * NH * NH;
        const float* WqL = Wq + (size_t)l * NTYPE * NH * NH;
        const float* WvL = Wv + (size_t)l * NTYPE * NH * NH;
        const float* WaL = Wa + (size_t)l * NTYPE * NH * NH;
        const float* bkL = bk + (size_t)l * NTYPE * NH;
        const float* bqL = bq + (size_t)l * NTYPE * NH;
        const float* bvL = bv + (size_t)l * NTYPE * NH;
        const float* baL = ba + (size_t)l * NTYPE * NH;

        GNN_rte_tab<<<240, 128, 0, stream>>>(rte_emb, rte_W + (size_t)l * NH * NH,
                                             rte_b + (size_t)l * NH, rtab);
        GNN_rte_proj<<<dim3(240, NTYPE * 2), 128, 0, stream>>>(rtab, WkL, WvL, RK, RV);

        GNN_ptype_gemm<1><<<ggrid, 256, 0, stream>>>(hin, NH, WqL, bqL, nullptr, nullptr,
                                                     nperm, ncur, Qn);
        GNN_ptype_gemm<1><<<ggrid, 256, 0, stream>>>(hin, NH, WkL, bkL, nullptr, nullptr,
                                                     nperm, ncur, Kn);
        GNN_ptype_gemm<1><<<ggrid, 256, 0, stream>>>(hin, NH, WvL, bvL, nullptr, nullptr,
                                                     nperm, ncur, Vn);

        hipMemsetAsync(amax, 0, (size_t)NN * (NHEAD + NHEAD + NH) * 4, stream);

        GNN_edge_att<<<(NE + EPB - 1) / EPB, 128, 0, stream>>>(
            Kn, Qn, RK, eperm, esrc, edst, edge_type, edge_time, node_type,
            rel_att + (size_t)l * NREL * NHEAD * DK * DK,
            rel_pri + (size_t)l * NREL * NHEAD, att, amax);
        GNN_edge_msg<<<(NE + EPB - 1) / EPB, 128, 0, stream>>>(
            Vn, RV, eperm, esrc, edst, edge_type, edge_time, node_type,
            rel_msg + (size_t)l * NREL * NHEAD * DK * DK, att, amax, denom, aggr);

        GNN_norm_gelu<<<(NN * NH + 255) / 256, 256, 0, stream>>>(denom, aggr);

        float* hout = (l == 0) ? hB : (float*)d_out;
        GNN_ptype_gemm<2><<<ggrid, 256, 0, stream>>>(aggr, NH, WaL, baL,
                                                     skip + (size_t)l * NTYPE, hin,
                                                     nperm, ncur, hout);
        hin = hout;
    }
}

// Round 3
// 1340.110 us; speedup vs baseline: 1.4980x; 1.4980x over previous
//
#include <hip/hip_runtime.h>
#include <math.h>

// ---- problem constants ----
#define NN     50000
#define NE     400000
#define INDIM  256
#define NH     128
#define NTYPE  4
#define NREL   5
#define NHEAD  4
#define DK     32
#define RSQRT_DK 0.17677669529663687f
#define BN     64
#define NSCAN_BLK ((NN + 255) / 256)   // 196

__device__ __forceinline__ float gelu_f(float x){
    return 0.5f * x * (1.0f + erff(x * 0.70710678118654752f));
}

// ---------------- node bucketing by type (for per-type GEMMs) ----------------
__global__ void GNN_nscatter(const int* __restrict__ ntype, int* __restrict__ ncur,
                             int* __restrict__ nperm){
    __shared__ int lcnt[4], lbase[4];
    int tid = threadIdx.x;
    if (tid < 4) lcnt[tid] = 0;
    __syncthreads();
    int n = blockIdx.x * 256 + tid;
    int t = 0, lpos = 0;
    bool ok = (n < NN);
    if (ok){ t = ntype[n]; lpos = atomicAdd(&lcnt[t], 1); }
    __syncthreads();
    if (tid < 4 && lcnt[tid] > 0) lbase[tid] = atomicAdd(&ncur[tid], lcnt[tid]);
    __syncthreads();
    if (ok) nperm[t * NN + lbase[t] + lpos] = n;
}

// ---------------- CSR by destination (built once per call) ----------------
__global__ void GNN_deg(const int* __restrict__ edst, int* __restrict__ deg){
    int e = blockIdx.x * 256 + threadIdx.x;
    if (e < NE) atomicAdd(&deg[edst[e]], 1);
}

__global__ void GNN_scan1(const int* __restrict__ deg, int* __restrict__ rowptr,
                          int* __restrict__ bsum){
    __shared__ int s[256];
    int g = blockIdx.x * 256 + threadIdx.x;
    int v = (g < NN) ? deg[g] : 0;
    s[threadIdx.x] = v;
    __syncthreads();
    for (int off = 1; off < 256; off <<= 1){
        int t = (threadIdx.x >= off) ? s[threadIdx.x - off] : 0;
        __syncthreads();
        s[threadIdx.x] += t;
        __syncthreads();
    }
    if (g < NN) rowptr[g] = s[threadIdx.x] - v;           // block-local exclusive
    if (threadIdx.x == 255) bsum[blockIdx.x] = s[255];
}

__global__ void GNN_scan2(const int* __restrict__ bsum, int* __restrict__ bbase){
    __shared__ int s[256];
    int v = (threadIdx.x < NSCAN_BLK) ? bsum[threadIdx.x] : 0;
    s[threadIdx.x] = v;
    __syncthreads();
    for (int off = 1; off < 256; off <<= 1){
        int t = (threadIdx.x >= off) ? s[threadIdx.x - off] : 0;
        __syncthreads();
        s[threadIdx.x] += t;
        __syncthreads();
    }
    bbase[threadIdx.x] = s[threadIdx.x] - v;              // exclusive
}

__global__ void GNN_scan3(int* __restrict__ rowptr, const int* __restrict__ bbase){
    int g = blockIdx.x * 256 + threadIdx.x;
    if (g < NN) rowptr[g] += bbase[blockIdx.x];
    if (g == 0) rowptr[NN] = NE;
}

__global__ void GNN_csr_scatter(const int* __restrict__ edst, const int* __restrict__ rowptr,
                                int* __restrict__ cursor, int* __restrict__ csr_e){
    int e = blockIdx.x * 256 + threadIdx.x;
    if (e >= NE) return;
    int d = edst[e];
    int pos = atomicAdd(&cursor[d], 1);
    csr_e[rowptr[d] + pos] = e;
}

// ------------- per-type tiled GEMM: OUT[n,:] = epilogue( X[n,:] @ W[type(n)] + b[type(n)] )
// MODE 0: gelu(.)   MODE 1: identity   MODE 2: (.)*sig(skip[t]) + Hprev*(1-sig(skip[t]))
template<int MODE>
__global__ __launch_bounds__(256) void GNN_ptype_gemm(
    const float* __restrict__ X, int K,
    const float* __restrict__ Wall, const float* __restrict__ ball,
    const float* __restrict__ skiprow, const float* __restrict__ Hprev,
    const int* __restrict__ nperm, const int* __restrict__ counts,
    float* __restrict__ OUT)
{
    int t = blockIdx.y;
    int cnt = counts[t];
    int rbase = blockIdx.x * BN;
    if (rbase >= cnt) return;
    const float* W = Wall + (size_t)t * K * NH;
    __shared__ float Xs[BN][33];
    __shared__ float Ws[32][NH];
    __shared__ int nids[BN];
    int tid = threadIdx.x;
    if (tid < BN){
        int idx = rbase + tid;
        nids[tid] = (idx < cnt) ? nperm[t * NN + idx] : -1;
    }
    int cq = tid & 31;
    int rq = tid >> 5;
    float acc[8][4];
    #pragma unroll
    for (int i = 0; i < 8; i++){ acc[i][0]=0.f; acc[i][1]=0.f; acc[i][2]=0.f; acc[i][3]=0.f; }
    __syncthreads();
    for (int k0 = 0; k0 < K; k0 += 32){
        {
            int lr = tid >> 3;
            int lc = (tid & 7) * 4;
            #pragma unroll
            for (int h2 = 0; h2 < 2; h2++){
                int r = lr + 32 * h2;
                int nid = nids[r];
                float4 xv = make_float4(0.f, 0.f, 0.f, 0.f);
                if (nid >= 0) xv = *(const float4*)(X + (size_t)nid * K + k0 + lc);
                Xs[r][lc+0]=xv.x; Xs[r][lc+1]=xv.y; Xs[r][lc+2]=xv.z; Xs[r][lc+3]=xv.w;
            }
        }
        {
            int wr = tid >> 5;
            int wc = (tid & 31) * 4;
            #pragma unroll
            for (int h2 = 0; h2 < 4; h2++){
                int r = wr + 8 * h2;
                *(float4*)&Ws[r][wc] = *(const float4*)(W + (size_t)(k0 + r) * NH + wc);
            }
        }
        __syncthreads();
        #pragma unroll
        for (int kk = 0; kk < 32; kk++){
            float4 wv = *(const float4*)&Ws[kk][cq * 4];
            #pragma unroll
            for (int i = 0; i < 8; i++){
                float xv = Xs[rq + 8*i][kk];
                acc[i][0] += xv * wv.x; acc[i][1] += xv * wv.y;
                acc[i][2] += xv * wv.z; acc[i][3] += xv * wv.w;
            }
        }
        __syncthreads();
    }
    float b0 = ball[t*NH + cq*4 + 0];
    float b1 = ball[t*NH + cq*4 + 1];
    float b2 = ball[t*NH + cq*4 + 2];
    float b3 = ball[t*NH + cq*4 + 3];
    float a_t = 0.f, one_m = 0.f;
    if (MODE == 2){ a_t = 1.f / (1.f + expf(-skiprow[t])); one_m = 1.f - a_t; }
    #pragma unroll
    for (int i = 0; i < 8; i++){
        int r = rq + 8*i;
        int nid = nids[r];
        if (nid < 0) continue;
        float v0 = acc[i][0] + b0, v1 = acc[i][1] + b1;
        float v2 = acc[i][2] + b2, v3 = acc[i][3] + b3;
        if (MODE == 0){ v0 = gelu_f(v0); v1 = gelu_f(v1); v2 = gelu_f(v2); v3 = gelu_f(v3); }
        if (MODE == 2){
            float4 hp = *(const float4*)(Hprev + (size_t)nid * NH + cq * 4);
            v0 = v0 * a_t + hp.x * one_m; v1 = v1 * a_t + hp.y * one_m;
            v2 = v2 * a_t + hp.z * one_m; v3 = v3 * a_t + hp.w * one_m;
        }
        *(float4*)(OUT + (size_t)nid * NH + cq * 4) = make_float4(v0, v1, v2, v3);
    }
}

// ------------- RTE tables ----------------
__global__ void GNN_rte_tab(const float* __restrict__ rte_emb, const float* __restrict__ rW,
                            const float* __restrict__ rb, float* __restrict__ tab){
    int m = blockIdx.x, j = threadIdx.x;
    __shared__ float e[NH];
    e[j] = rte_emb[m * NH + j];
    __syncthreads();
    float a = rb[j];
    #pragma unroll 8
    for (int d = 0; d < NH; d++) a += e[d] * rW[d * NH + j];
    tab[m * NH + j] = a;
}

__global__ void GNN_rte_proj(const float* __restrict__ tab, const float* __restrict__ WkL,
                             const float* __restrict__ WvL, float* __restrict__ RK,
                             float* __restrict__ RV){
    int m = blockIdx.x, j = threadIdx.x;
    int sel = blockIdx.y; int t = sel >> 1; int which = sel & 1;
    const float* W = (which ? WvL : WkL) + (size_t)t * NH * NH;
    float* O = which ? RV : RK;
    __shared__ float e[NH];
    e[j] = tab[m * NH + j];
    __syncthreads();
    float a = 0.f;
    #pragma unroll 8
    for (int d = 0; d < NH; d++) a += e[d] * W[d * NH + j];
    O[(size_t)(t * 240 + m) * NH + j] = a;
}

// ------------- QA[r][i][h*32+d] = sum_c rel_att[r][h][d][c] * q[i][h*32+c] -----------
__global__ __launch_bounds__(256) void GNN_qa(
    const float* __restrict__ Qn, const float* __restrict__ relA, float* __restrict__ QA)
{
    __shared__ float At[NHEAD * DK * DK];     // transposed: At[h*1024 + c*32 + d]
    __shared__ float Qs[64 * 132];
    int r = blockIdx.y;
    int nb = blockIdx.x * 64;
    int tid = threadIdx.x;
    const float* Ar = relA + (size_t)r * NHEAD * DK * DK;
    for (int x = tid; x < NHEAD * DK * DK; x += 256){
        int hh = x >> 10, rem = x & 1023, dd = rem >> 5, cc = rem & 31;
        At[hh * 1024 + cc * 32 + dd] = Ar[x];
    }
    for (int x = tid; x < 64 * 32; x += 256){
        int row = x >> 5, c4 = (x & 31) * 4;
        int node = nb + row;
        float4 qv = make_float4(0.f, 0.f, 0.f, 0.f);
        if (node < NN) qv = *(const float4*)(Qn + (size_t)node * NH + c4);
        float* dp = &Qs[row * 132 + c4];
        dp[0] = qv.x; dp[1] = qv.y; dp[2] = qv.z; dp[3] = qv.w;
    }
    __syncthreads();
    int cq = tid & 31, rq = tid >> 5;
    int h = cq >> 3, dl = (cq & 7) * 4;
    float acc[8][4];
    #pragma unroll
    for (int i = 0; i < 8; i++){ acc[i][0]=0.f; acc[i][1]=0.f; acc[i][2]=0.f; acc[i][3]=0.f; }
    for (int c = 0; c < DK; c++){
        float4 av = *(const float4*)&At[h * 1024 + c * 32 + dl];
        #pragma unroll
        for (int i = 0; i < 8; i++){
            float qv = Qs[(rq + 8*i) * 132 + h * 32 + c];
            acc[i][0] += qv * av.x; acc[i][1] += qv * av.y;
            acc[i][2] += qv * av.z; acc[i][3] += qv * av.w;
        }
    }
    #pragma unroll
    for (int i = 0; i < 8; i++){
        int node = nb + rq + 8*i;
        if (node >= NN) continue;
        *(float4*)(QA + ((size_t)r * NN + node) * NH + cq * 4) =
            make_float4(acc[i][0], acc[i][1], acc[i][2], acc[i][3]);
    }
}

// ------------- E1: att[e,h] = (Kn[src]+RK[st,tm]) . QA[r][dst]  (32 lanes/edge, no LDS) ----
__global__ __launch_bounds__(256) void GNN_edge_att(
    const float* __restrict__ Kn, const float* __restrict__ RK, const float* __restrict__ QA,
    const int* __restrict__ esrc, const int* __restrict__ edst,
    const int* __restrict__ etype, const int* __restrict__ etime,
    const int* __restrict__ ntype, const float* __restrict__ relP,
    float* __restrict__ att)
{
    int tid = threadIdx.x;
    int e = blockIdx.x * 8 + (tid >> 5);
    if (e >= NE) return;
    int lane = tid & 31;
    int s = esrc[e], d = edst[e], r = etype[e], tm = etime[e];
    int st = ntype[s];
    float4 k4 = *(const float4*)(Kn + (size_t)s * NH + lane * 4);
    float4 rk = *(const float4*)(RK + (size_t)(st * 240 + tm) * NH + lane * 4);
    float4 qa = *(const float4*)(QA + ((size_t)r * NN + d) * NH + lane * 4);
    float pv = (k4.x + rk.x) * qa.x + (k4.y + rk.y) * qa.y
             + (k4.z + rk.z) * qa.z + (k4.w + rk.w) * qa.w;
    pv += __shfl_xor(pv, 4);
    pv += __shfl_xor(pv, 2);
    pv += __shfl_xor(pv, 1);
    if ((lane & 7) == 0){
        int head = lane >> 3;
        att[(size_t)e * NHEAD + head] = pv * relP[r * NHEAD + head] * RSQRT_DK;
    }
}

// ------------- E2a: per-node softmax + per-relation aggregation of raw v (no atomics) -----
__global__ __launch_bounds__(256) void GNN_node_aggr(
    const float* __restrict__ att, const float* __restrict__ Vn, const float* __restrict__ RV,
    const int* __restrict__ rowptr, const int* __restrict__ csr_e,
    const int* __restrict__ esrc, const int* __restrict__ etype,
    const int* __restrict__ etime, const int* __restrict__ ntype,
    float* __restrict__ P)
{
    int tid = threadIdx.x;
    int i = blockIdx.x * 8 + (tid >> 5);
    if (i >= NN) return;
    int lane = tid & 31;
    int head = lane >> 3;
    int beg = rowptr[i], end = rowptr[i + 1];
    // pass 1: segment max (all 8 lanes of a head read the same att value)
    float mx = -3.4e38f;
    for (int k = beg; k < end; k++){
        int e = csr_e[k];
        mx = fmaxf(mx, att[(size_t)e * NHEAD + head]);
    }
    // pass 2: accumulate exp-weighted raw v per relation, in registers
    float4 acc[NREL];
    #pragma unroll
    for (int rr = 0; rr < NREL; rr++) acc[rr] = make_float4(0.f, 0.f, 0.f, 0.f);
    float den = 0.f;
    for (int k = beg; k < end; k++){
        int e = csr_e[k];
        int s = esrc[e], r = etype[e], tm = etime[e];
        int st = ntype[s];
        float ex = expf(att[(size_t)e * NHEAD + head] - mx);
        den += ex;
        float4 v4 = *(const float4*)(Vn + (size_t)s * NH + lane * 4);
        float4 rv = *(const float4*)(RV + (size_t)(st * 240 + tm) * NH + lane * 4);
        float vx = v4.x + rv.x, vy = v4.y + rv.y, vz = v4.z + rv.z, vw = v4.w + rv.w;
        #pragma unroll
        for (int rr = 0; rr < NREL; rr++){
            float w = (rr == r) ? ex : 0.f;     // predicated, keeps acc in registers
            acc[rr].x += w * vx; acc[rr].y += w * vy;
            acc[rr].z += w * vz; acc[rr].w += w * vw;
        }
    }
    float inv = 1.f / (den + 1e-16f);
    #pragma unroll
    for (int rr = 0; rr < NREL; rr++){
        *(float4*)(P + ((size_t)rr * NN + i) * NH + lane * 4) =
            make_float4(acc[rr].x * inv, acc[rr].y * inv, acc[rr].z * inv, acc[rr].w * inv);
    }
}

// ------------- E2b: aggr[i][h*32+c] = gelu( sum_r sum_d P[r][i][h*32+d] * M_r[h][d][c] ) ---
__global__ __launch_bounds__(256) void GNN_pm(
    const float* __restrict__ P, const float* __restrict__ relM, float* __restrict__ aggr)
{
    __shared__ float Ms[NHEAD * DK * DK];
    __shared__ float Ps[64 * 132];
    int tid = threadIdx.x;
    int nb = blockIdx.x * 64;
    int cq = tid & 31, rq = tid >> 5;
    int h = cq >> 3, cl = (cq & 7) * 4;
    float acc[8][4];
    #pragma unroll
    for (int i = 0; i < 8; i++){ acc[i][0]=0.f; acc[i][1]=0.f; acc[i][2]=0.f; acc[i][3]=0.f; }
    for (int r = 0; r < NREL; r++){
        const float* Mr = relM + (size_t)r * NHEAD * DK * DK;
        for (int x = tid; x < NHEAD * DK * DK; x += 256) Ms[x] = Mr[x];
        for (int x = tid; x < 64 * 32; x += 256){
            int row = x >> 5, c4 = (x & 31) * 4;
            int node = nb + row;
            float4 pv = make_float4(0.f, 0.f, 0.f, 0.f);
            if (node < NN) pv = *(const float4*)(P + ((size_t)r * NN + node) * NH + c4);
            float* dp = &Ps[row * 132 + c4];
            dp[0] = pv.x; dp[1] = pv.y; dp[2] = pv.z; dp[3] = pv.w;
        }
        __syncthreads();
        for (int d = 0; d < DK; d++){
            float4 mv = *(const float4*)&Ms[h * 1024 + d * 32 + cl];
            #pragma unroll
            for (int i = 0; i < 8; i++){
                float pval = Ps[(rq + 8*i) * 132 + h * 32 + d];
                acc[i][0] += pval * mv.x; acc[i][1] += pval * mv.y;
                acc[i][2] += pval * mv.z; acc[i][3] += pval * mv.w;
            }
        }
        __syncthreads();
    }
    #pragma unroll
    for (int i = 0; i < 8; i++){
        int node = nb + rq + 8*i;
        if (node >= NN) continue;
        *(float4*)(aggr + (size_t)node * NH + cq * 4) =
            make_float4(gelu_f(acc[i][0]), gelu_f(acc[i][1]),
                        gelu_f(acc[i][2]), gelu_f(acc[i][3]));
    }
}

extern "C" void kernel_launch(void* const* d_in, const int* in_sizes, int n_in,
                              void* d_out, int out_size, void* d_ws, size_t ws_size,
                              hipStream_t stream)
{
    const float* node_feature = (const float*)d_in[0];
    const float* adapt_W = (const float*)d_in[1];
    const float* adapt_b = (const float*)d_in[2];
    const float* Wk = (const float*)d_in[3];
    const float* bk = (const float*)d_in[4];
    const float* Wq = (const float*)d_in[5];
    const float* bq = (const float*)d_in[6];
    const float* Wv = (const float*)d_in[7];
    const float* bv = (const float*)d_in[8];
    const float* Wa = (const float*)d_in[9];
    const float* ba = (const float*)d_in[10];
    const float* rel_pri = (const float*)d_in[11];
    const float* rel_att = (const float*)d_in[12];
    const float* rel_msg = (const float*)d_in[13];
    const float* skip = (const float*)d_in[14];
    const float* rte_emb = (const float*)d_in[15];
    const float* rte_W = (const float*)d_in[16];
    const float* rte_b = (const float*)d_in[17];
    const int* node_type = (const int*)d_in[18];
    const int* edge_index = (const int*)d_in[19];
    const int* edge_type = (const int*)d_in[20];
    const int* edge_time = (const int*)d_in[21];
    const int* esrc = edge_index;          // row 0 = source j
    const int* edst = edge_index + NE;     // row 1 = target i

    char* p = (char*)d_ws;
    auto alloc = [&](size_t bytes) -> char* {
        char* r = p; p += (bytes + 255) & ~(size_t)255; return r;
    };
    float* hA    = (float*)alloc((size_t)NN * NH * 4);
    float* Qn    = (float*)alloc((size_t)NN * NH * 4);      // att aliases this (E1..E2a window)
    float* Kn    = (float*)alloc((size_t)NN * NH * 4);      // aggr aliases this (E2b..Wa window)
    float* Vn    = (float*)alloc((size_t)NN * NH * 4);
    float* QA    = (float*)alloc((size_t)NREL * NN * NH * 4);  // P aliases this (E2a..E2b)
    float* rtab  = (float*)alloc((size_t)240 * NH * 4);
    float* RK    = (float*)alloc((size_t)NTYPE * 240 * NH * 4);
    float* RV    = (float*)alloc((size_t)NTYPE * 240 * NH * 4);
    int* nperm   = (int*)alloc((size_t)NTYPE * NN * 4);
    int* rowptr  = (int*)alloc((size_t)(NN + 1) * 4);
    int* csr_e   = (int*)alloc((size_t)NE * 4);
    int* deg     = (int*)alloc((size_t)2 * NN * 4);   // deg+cursor in ONE block: the single
    int* cursor  = deg + NN;                          // memset covers both exactly (round-2
                                                      // bug: separate allocs got 256B-rounded,
                                                      // leaving 192 B of cursor poisoned)
    int* bsum    = (int*)alloc(256 * 4);
    int* bbase   = (int*)alloc(256 * 4);
    int* ncur    = (int*)alloc(64);
    float* att   = Qn;      // [NE*NHEAD] = 6.4 MB < 25.6 MB
    float* Pbuf  = QA;      // per-(relation,node) aggregate
    float* aggr  = Kn;

    hipMemsetAsync(ncur, 0, 64, stream);
    hipMemsetAsync(deg, 0, (size_t)2 * NN * 4, stream);     // covers deg AND cursor exactly

    GNN_nscatter<<<(NN + 255) / 256, 256, 0, stream>>>(node_type, ncur, nperm);
    GNN_deg<<<(NE + 255) / 256, 256, 0, stream>>>(edst, deg);
    GNN_scan1<<<NSCAN_BLK, 256, 0, stream>>>(deg, rowptr, bsum);
    GNN_scan2<<<1, 256, 0, stream>>>(bsum, bbase);
    GNN_scan3<<<NSCAN_BLK, 256, 0, stream>>>(rowptr, bbase);
    GNN_csr_scatter<<<(NE + 255) / 256, 256, 0, stream>>>(edst, rowptr, cursor, csr_e);

    dim3 ggrid((NN + BN - 1) / BN, NTYPE);
    GNN_ptype_gemm<0><<<ggrid, 256, 0, stream>>>(node_feature, INDIM, adapt_W, adapt_b,
                                                 nullptr, nullptr, nperm, ncur, hA);
    const float* hin = hA;
    for (int l = 0; l < 2; l++){
        const float* WkL = Wk + (size_t)l * NTYPE * NH * NH;
        const float* WqL = Wq + (size_t)l * NTYPE * NH * NH;
        const float* WvL = Wv + (size_t)l * NTYPE * NH * NH;
        const float* WaL = Wa + (size_t)l * NTYPE * NH * NH;
        const float* bkL = bk + (size_t)l * NTYPE * NH;
        const float* bqL = bq + (size_t)l * NTYPE * NH;
        const float* bvL = bv + (size_t)l * NTYPE * NH;
        const float* baL = ba + (size_t)l * NTYPE * NH;
        const float* relA = rel_att + (size_t)l * NREL * NHEAD * DK * DK;
        const float* relM = rel_msg + (size_t)l * NREL * NHEAD * DK * DK;
        const float* relP = rel_pri + (size_t)l * NREL * NHEAD;

        GNN_rte_tab<<<240, 128, 0, stream>>>(rte_emb, rte_W + (size_t)l * NH * NH,
                                             rte_b + (size_t)l * NH, rtab);
        GNN_rte_proj<<<dim3(240, NTYPE * 2), 128, 0, stream>>>(rtab, WkL, WvL, RK, RV);

        GNN_ptype_gemm<1><<<ggrid, 256, 0, stream>>>(hin, NH, WqL, bqL, nullptr, nullptr,
                                                     nperm, ncur, Qn);
        GNN_qa<<<dim3((NN + 63) / 64, NREL), 256, 0, stream>>>(Qn, relA, QA);
        GNN_ptype_gemm<1><<<ggrid, 256, 0, stream>>>(hin, NH, WkL, bkL, nullptr, nullptr,
                                                     nperm, ncur, Kn);
        GNN_ptype_gemm<1><<<ggrid, 256, 0, stream>>>(hin, NH, WvL, bvL, nullptr, nullptr,
                                                     nperm, ncur, Vn);

        GNN_edge_att<<<(NE + 7) / 8, 256, 0, stream>>>(
            Kn, RK, QA, esrc, edst, edge_type, edge_time, node_type, relP, att);

        GNN_node_aggr<<<(NN + 7) / 8, 256, 0, stream>>>(
            att, Vn, RV, rowptr, csr_e, esrc, edge_type, edge_time, node_type, Pbuf);

        GNN_pm<<<(NN + 63) / 64, 256, 0, stream>>>(Pbuf, relM, aggr);

        float* hout = (l == 0) ? hA : (float*)d_out;   // l==0 in-place on hA is safe:
        GNN_ptype_gemm<2><<<ggrid, 256, 0, stream>>>(  // epilogue reads Hprev[nid,cols] then
            aggr, NH, WaL, baL, skip + (size_t)l * NTYPE, hin,   // writes same elems, same thread
            nperm, ncur, hout);
        hin = hout;
    }
}